// Round 3
// baseline (116.549 us; speedup 1.0000x reference)
//
#include <hip/hip_runtime.h>

// KDPointToPointLoss: B=8, C=3, N=M=4096, fp32.
// loss[b] = (1/(3N)) * sum_n min_m ||src[b,:,n] - tgt[b,:,m]||^2
// Cross-term form: ||s-t||^2 = s^2 + (t^2 - 2 s.t). Pack (tx,ty,tz,t^2) as
// float4; inner loop is 3 fma + amortized min3 per target.
//
// R3 fix: each block covers ALL 4096 targets (min must be complete per
// source before summing). Occupancy via 1024-thread blocks:
// 512 blocks x 16 waves = 8192 waves = 100% of 256 CU x 32 slots.

#define B_ 8
#define N_ 4096
#define M_ 4096
#define CH_STRIDE 4096
#define BATCH_STRIDE 12288

// ---- pass 1: pack targets into (x, y, z, x^2+y^2+z^2) ----
__global__ void pack_tgt_kernel(const float* __restrict__ tgt,
                                float4* __restrict__ packed) {
    int i = blockIdx.x * 256 + threadIdx.x;       // 0..32767
    int b = i >> 12;
    int m = i & (M_ - 1);
    const float* tb = tgt + b * BATCH_STRIDE;
    float x = tb[m];
    float y = tb[m + CH_STRIDE];
    float z = tb[m + 2 * CH_STRIDE];
    packed[i] = make_float4(x, y, z, x * x + y * y + z * z);
}

// ---- pass 2: main NN loop ----
// block = 1024 threads = 16 waves; 64 blocks/batch x 8 batches = 512 blocks.
// lane ls = source (64 per block), wave w = 256-target chunk (16 chunks =
// all 4096 targets). Target loads are wave-uniform -> broadcast transaction.
__global__ __launch_bounds__(1024, 8)
void nn_loss_main(const float* __restrict__ src,
                  const float4* __restrict__ packed,
                  float* __restrict__ partial) {
    const int tid  = threadIdx.x;
    const int blk  = blockIdx.x;
    const int b    = blk >> 6;            // 0..7
    const int sgrp = blk & 63;            // source group of 64
    const int ls   = tid & 63;
    const int w    = tid >> 6;            // wave id 0..15

    const int n = (sgrp << 6) + ls;
    const float* sb = src + b * BATCH_STRIDE;
    const float sx = sb[n];
    const float sy = sb[n + CH_STRIDE];
    const float sz = sb[n + 2 * CH_STRIDE];
    const float ax = -2.0f * sx, ay = -2.0f * sy, az = -2.0f * sz;
    const float s2 = sx * sx + sy * sy + sz * sz;

    // this wave's 256 targets
    const float4* tp = packed + (b << 12) + (w << 8);

    float best0 = 3.4e38f, best1 = 3.4e38f;
    #pragma unroll 2
    for (int m = 0; m < 256; m += 4) {
        float4 t0 = tp[m];
        float4 t1 = tp[m + 1];
        float4 t2 = tp[m + 2];
        float4 t3 = tp[m + 3];
        float d0 = fmaf(ax, t0.x, fmaf(ay, t0.y, fmaf(az, t0.z, t0.w)));
        float d1 = fmaf(ax, t1.x, fmaf(ay, t1.y, fmaf(az, t1.z, t1.w)));
        float d2 = fmaf(ax, t2.x, fmaf(ay, t2.y, fmaf(az, t2.z, t2.w)));
        float d3 = fmaf(ax, t3.x, fmaf(ay, t3.y, fmaf(az, t3.z, t3.w)));
        best0 = fminf(fminf(best0, d0), d1);   // v_min3_f32
        best1 = fminf(fminf(best1, d2), d3);
    }
    float best = fminf(best0, best1);

    // min across the 16 waves for each of the 64 sources
    __shared__ float red[1024];
    red[(w << 6) + ls] = best;
    __syncthreads();

    if (tid < 64) {
        float mn = red[tid];
        #pragma unroll
        for (int j = 1; j < 16; ++j)
            mn = fminf(mn, red[(j << 6) + tid]);
        mn += s2;                         // complete min-d2 for source `tid`
        // wave-64 sum across the 64 sources
        #pragma unroll
        for (int off = 32; off > 0; off >>= 1)
            mn += __shfl_down(mn, off, 64);
        if (tid == 0)
            partial[blk] = mn;
    }
}

// ---- pass 3: reduce 64 partials per batch -> loss ----
__global__ void reduce_kernel(const float* __restrict__ partial,
                              float* __restrict__ out) {
    const int b = blockIdx.x;             // 0..7
    const int tid = threadIdx.x;          // 0..63
    float v = partial[(b << 6) + tid];
    #pragma unroll
    for (int off = 32; off > 0; off >>= 1)
        v += __shfl_down(v, off, 64);
    if (tid == 0)
        out[b] = v * (1.0f / (3.0f * (float)N_));
}

extern "C" void kernel_launch(void* const* d_in, const int* in_sizes, int n_in,
                              void* d_out, int out_size, void* d_ws, size_t ws_size,
                              hipStream_t stream) {
    const float* src = (const float*)d_in[0];   // [8,3,4096]
    const float* tgt = (const float*)d_in[1];   // [8,3,4096]
    float* out = (float*)d_out;                 // [8]

    float4* packed  = (float4*)d_ws;            // 32768 float4 = 512 KB
    float*  partial = (float*)((char*)d_ws + (size_t)B_ * M_ * sizeof(float4)); // 512 floats

    pack_tgt_kernel<<<128, 256, 0, stream>>>(tgt, packed);
    nn_loss_main<<<512, 1024, 0, stream>>>(src, packed, partial);
    reduce_kernel<<<B_, 64, 0, stream>>>(partial, out);
}

// Round 4
// 67.407 us; speedup vs baseline: 1.7290x; 1.7290x over previous
//
#include <hip/hip_runtime.h>

// KDPointToPointLoss: B=8, C=3, N=M=4096, fp32.
// loss[b] = (1/(3N)) * sum_n min_m ||s_n - t_m||^2
//         = (1/(3N)) * sum_n [ s_n^2 + min_m (t_m^2 - 2 s_n . t_m) ]
//
// R4: wave-uniform GLOBAL loads were the bottleneck (L1 return path moves
// 64x16B per instr even when all lanes read the same address ~16cyc/instr).
// Fix: broadcast targets from LDS (same-address LDS read dedups), and
// amortize each broadcast over 4 sources per lane.
//
// main grid: 512 blocks = 8 batches x 4 target-quarters x 16 source-groups.
// block: 1024 thr (16 waves). Stage 1024 targets (16KB) in LDS; each wave
// sweeps 64 targets vs 256 sources (4 per lane). Per-source min over the
// quarter (+s^2) -> partial[quarter][b][src]; pass 3 min-combines quarters
// and sums.

#define B_ 8
#define N_ 4096
#define M_ 4096
#define CH 4096
#define BS 12288
#define TQ 1024          // targets per block
#define BIG 3.4e38f

__global__ __launch_bounds__(1024, 8)   // 8 waves/EU -> 2 blocks/CU, VGPR<=64
void nn_loss_main(const float* __restrict__ src,
                  const float* __restrict__ tgt,
                  float* __restrict__ partial) {
    __shared__ __align__(16) char smem[TQ * 16];   // 16 KB: stage, then red
    float4* stage = (float4*)smem;
    float*  red   = (float*)smem;

    const int tid  = threadIdx.x;
    const int blk  = blockIdx.x;
    const int b    = blk >> 6;
    const int rest = blk & 63;
    const int q    = rest >> 4;          // target quarter 0..3
    const int sgrp = rest & 15;          // source group 0..15
    const int ls   = tid & 63;
    const int w    = tid >> 6;           // wave 0..15

    // ---- stage this quarter's targets: (x,y,z, x^2+y^2+z^2) ----
    {
        const float* tb = tgt + b * BS;
        const int m = (q << 10) + tid;
        float x = tb[m], y = tb[m + CH], z = tb[m + 2 * CH];
        stage[tid] = make_float4(x, y, z, x * x + y * y + z * z);
    }

    // ---- load 4 sources per lane ----
    const float* sb = src + b * BS;
    float ax[4], ay[4], az[4], s2[4];
    #pragma unroll
    for (int j = 0; j < 4; ++j) {
        int n = (sgrp << 8) + (j << 6) + ls;
        float sx = sb[n], sy = sb[n + CH], sz = sb[n + 2 * CH];
        ax[j] = -2.0f * sx; ay[j] = -2.0f * sy; az[j] = -2.0f * sz;
        s2[j] = sx * sx + sy * sy + sz * sz;
    }

    __syncthreads();

    // ---- sweep this wave's 64 targets against 256 sources ----
    float best0[4], best1[4];
    #pragma unroll
    for (int j = 0; j < 4; ++j) { best0[j] = BIG; best1[j] = BIG; }

    const float4* tp = stage + (w << 6);
    #pragma unroll 4
    for (int i = 0; i < 64; i += 2) {
        float4 t0 = tp[i];
        float4 t1 = tp[i + 1];
        #pragma unroll
        for (int j = 0; j < 4; ++j) {
            float d0 = fmaf(ax[j], t0.x, fmaf(ay[j], t0.y, fmaf(az[j], t0.z, t0.w)));
            float d1 = fmaf(ax[j], t1.x, fmaf(ay[j], t1.y, fmaf(az[j], t1.z, t1.w)));
            best0[j] = fminf(best0[j], d0);      // two accumulators: deeper ILP
            best1[j] = fminf(best1[j], d1);
        }
    }

    __syncthreads();   // staging reads done; reuse smem as red[]

    // red[w*256 + j*64 + ls] = per-wave best (+ s^2, constant across waves)
    #pragma unroll
    for (int j = 0; j < 4; ++j)
        red[(w << 8) + (j << 6) + ls] = fminf(best0[j], best1[j]) + s2[j];

    __syncthreads();

    // combine across 16 waves; thread tid<256 handles source sgrp*256+tid
    if (tid < 256) {
        float mn = red[tid];
        #pragma unroll
        for (int v = 1; v < 16; ++v)
            mn = fminf(mn, red[(v << 8) + tid]);
        partial[(q << 15) + (b << 12) + (sgrp << 8) + tid] = mn;
    }
}

// ---- pass 3: min over 4 quarters per source, sum per batch ----
__global__ __launch_bounds__(1024)
void reduce_kernel(const float* __restrict__ partial,
                   float* __restrict__ out) {
    const int b = blockIdx.x;            // 0..7
    const int tid = threadIdx.x;         // 0..1023

    float acc = 0.0f;
    #pragma unroll
    for (int j = 0; j < 4; ++j) {
        int s = (j << 10) + tid;         // source index in batch
        int base = (b << 12) + s;
        float p0 = partial[base];
        float p1 = partial[(1 << 15) + base];
        float p2 = partial[(2 << 15) + base];
        float p3 = partial[(3 << 15) + base];
        acc += fminf(fminf(p0, p1), fminf(p2, p3));
    }

    // block sum: wave64 shfl -> 16 partials -> thread 0
    #pragma unroll
    for (int off = 32; off > 0; off >>= 1)
        acc += __shfl_down(acc, off, 64);

    __shared__ float red[16];
    if ((tid & 63) == 0) red[tid >> 6] = acc;
    __syncthreads();
    if (tid == 0) {
        float v = 0.0f;
        #pragma unroll
        for (int k = 0; k < 16; ++k) v += red[k];
        out[b] = v * (1.0f / (3.0f * (float)N_));
    }
}

extern "C" void kernel_launch(void* const* d_in, const int* in_sizes, int n_in,
                              void* d_out, int out_size, void* d_ws, size_t ws_size,
                              hipStream_t stream) {
    const float* src = (const float*)d_in[0];   // [8,3,4096]
    const float* tgt = (const float*)d_in[1];   // [8,3,4096]
    float* out = (float*)d_out;                 // [8]
    float* partial = (float*)d_ws;              // 4*8*4096 floats = 512 KB

    nn_loss_main<<<512, 1024, 0, stream>>>(src, tgt, partial);
    reduce_kernel<<<B_, 1024, 0, stream>>>(partial, out);
}

// Round 5
// 67.088 us; speedup vs baseline: 1.7373x; 1.0048x over previous
//
#include <hip/hip_runtime.h>

// KDPointToPointLoss: B=8, C=3, N=M=4096, fp32.
// loss[b] = (1/(3N)) * sum_n [ s_n^2 + min_m (t_m^2 - 2 s_n . t_m) ]
//
// R5: R4 was LDS-read-throughput-bound (each ds_read_b128 fed only 4
// sources; 2048 reads/CU x 12cyc = 24.6K cyc > VALU 17.4K). Now 8 sources
// per lane -> half the LDS reads per pair; VALU-bound at ~15K cyc (~6us).
//
// grid: 512 blocks = 8 batches x 8 target-eighths x 8 source-groups.
// block: 512 thr (8 waves), 4 blocks/CU (100% wave slots). Stage 512
// targets (8KB) as (x,y,z,t^2); wave sweeps 64 targets vs 512 sources
// (8/lane). Per-source min over eighth (+s^2) -> partial[e][b][src];
// pass 2 min-combines eighths and sums.

#define B_ 8
#define N_ 4096
#define CH 4096
#define BS 12288
#define TQ 512           // targets per block
#define BIG 3.4e38f

__global__ __launch_bounds__(512, 8)    // 8 waves/EU -> 4 blocks/CU, VGPR<=64
void nn_loss_main(const float* __restrict__ src,
                  const float* __restrict__ tgt,
                  float* __restrict__ partial) {
    __shared__ __align__(16) char smem[8 * TQ * 4];   // 16 KB: stage(8K), red(16K)
    float4* stage = (float4*)smem;
    float*  red   = (float*)smem;

    const int tid  = threadIdx.x;        // 0..511
    const int blk  = blockIdx.x;
    const int b    = blk >> 6;           // 0..7
    const int e    = (blk >> 3) & 7;     // target eighth 0..7
    const int sgrp = blk & 7;            // source group 0..7 (512 srcs each)
    const int ls   = tid & 63;
    const int w    = tid >> 6;           // wave 0..7

    // ---- stage this eighth's targets: (x,y,z, x^2+y^2+z^2) ----
    {
        const float* tb = tgt + b * BS;
        const int m = (e << 9) + tid;
        float x = tb[m], y = tb[m + CH], z = tb[m + 2 * CH];
        stage[tid] = make_float4(x, y, z, x * x + y * y + z * z);
    }

    // ---- load 8 sources per lane (store -2*coords; s^2 recomputed later) ----
    const float* sb = src + b * BS;
    float ax[8], ay[8], az[8];
    #pragma unroll
    for (int j = 0; j < 8; ++j) {
        int n = (sgrp << 9) + (j << 6) + ls;
        ax[j] = -2.0f * sb[n];
        ay[j] = -2.0f * sb[n + CH];
        az[j] = -2.0f * sb[n + 2 * CH];
    }

    __syncthreads();

    // ---- sweep this wave's 64 targets against 512 sources ----
    float best[8];
    #pragma unroll
    for (int j = 0; j < 8; ++j) best[j] = BIG;

    const float4* tp = stage + (w << 6);
    #pragma unroll 2
    for (int i = 0; i < 64; i += 2) {
        float4 t0 = tp[i];
        float4 t1 = tp[i + 1];
        #pragma unroll
        for (int j = 0; j < 8; ++j) {
            float d0 = fmaf(ax[j], t0.x, fmaf(ay[j], t0.y, fmaf(az[j], t0.z, t0.w)));
            float d1 = fmaf(ax[j], t1.x, fmaf(ay[j], t1.y, fmaf(az[j], t1.z, t1.w)));
            best[j] = fminf(fminf(best[j], d0), d1);   // v_min3_f32
        }
    }

    __syncthreads();   // staging reads done; reuse smem as red[8][512]

    // store best + s^2  (s^2 = 0.25*(ax^2+ay^2+az^2), exact pow2 scale)
    #pragma unroll
    for (int j = 0; j < 8; ++j) {
        float s2 = 0.25f * fmaf(ax[j], ax[j], fmaf(ay[j], ay[j], az[j] * az[j]));
        red[(w << 9) + (j << 6) + ls] = best[j] + s2;
    }

    __syncthreads();

    // combine across 8 waves; thread tid handles source sgrp*512+tid
    float mn = red[tid];
    #pragma unroll
    for (int v = 1; v < 8; ++v)
        mn = fminf(mn, red[(v << 9) + tid]);
    partial[(e << 15) + (b << 12) + (sgrp << 9) + tid] = mn;
}

// ---- pass 2: min over 8 eighths per source, sum per batch ----
__global__ __launch_bounds__(1024)
void reduce_kernel(const float* __restrict__ partial,
                   float* __restrict__ out) {
    const int b = blockIdx.x;            // 0..7
    const int tid = threadIdx.x;         // 0..1023

    float acc = 0.0f;
    #pragma unroll
    for (int j = 0; j < 4; ++j) {
        int base = (b << 12) + (j << 10) + tid;
        float mn = partial[base];
        #pragma unroll
        for (int e = 1; e < 8; ++e)
            mn = fminf(mn, partial[(e << 15) + base]);
        acc += mn;
    }

    #pragma unroll
    for (int off = 32; off > 0; off >>= 1)
        acc += __shfl_down(acc, off, 64);

    __shared__ float red[16];
    if ((tid & 63) == 0) red[tid >> 6] = acc;
    __syncthreads();
    if (tid == 0) {
        float v = 0.0f;
        #pragma unroll
        for (int k = 0; k < 16; ++k) v += red[k];
        out[b] = v * (1.0f / (3.0f * (float)N_));
    }
}

extern "C" void kernel_launch(void* const* d_in, const int* in_sizes, int n_in,
                              void* d_out, int out_size, void* d_ws, size_t ws_size,
                              hipStream_t stream) {
    const float* src = (const float*)d_in[0];   // [8,3,4096]
    const float* tgt = (const float*)d_in[1];   // [8,3,4096]
    float* out = (float*)d_out;                 // [8]
    float* partial = (float*)d_ws;              // 8*8*4096 floats = 1 MB

    nn_loss_main<<<512, 512, 0, stream>>>(src, tgt, partial);
    reduce_kernel<<<B_, 1024, 0, stream>>>(partial, out);
}